// Round 13
// baseline (246.448 us; speedup 1.0000x reference)
//
#include <hip/hip_runtime.h>
#include <hip/hip_bf16.h>
#include <math.h>

// B=8, S=512, HID=1024, NH=16, D=64, SPAN=512
// scale = 1/sqrt(64*3)  (pre-applied to Q and pq in proj epilogue)
#define SCALE 0.07216878364870323f
#define NEG_BIG -1e30f

typedef __attribute__((ext_vector_type(8))) short bf16x8;
typedef __attribute__((ext_vector_type(4))) short bf16x4;
typedef __attribute__((ext_vector_type(4))) float f32x4;
#define MFMA_BF16 __builtin_amdgcn_mfma_f32_16x16x32_bf16

static __device__ __forceinline__ float bf2f(__hip_bfloat16 x) { return __bfloat162float(x); }
static __device__ __forceinline__ __hip_bfloat16 f2bf(float x) { return __float2bfloat16(x); }
static __device__ __forceinline__ short f2bs(float x) {
  union { __hip_bfloat16 b; short s; } u; u.b = __float2bfloat16(x); return u.s;
}
static __device__ __forceinline__ float s2f(short v) {
  union { float f; unsigned u; } x; x.u = ((unsigned)(unsigned short)v) << 16; return x.f;
}
static __device__ __forceinline__ bf16x4 cvt4(float4 f) {
  bf16x4 r; r[0] = f2bs(f.x); r[1] = f2bs(f.y); r[2] = f2bs(f.z); r[3] = f2bs(f.w);
  return r;
}
static __device__ __forceinline__ bf16x8 ldg8(const __hip_bfloat16* p) {
  return *(const bf16x8*)p;
}
// async global->LDS, 16B per lane; LDS dest = wave-uniform base + lane*16
static __device__ __forceinline__ void gl_lds16(const __hip_bfloat16* g, __hip_bfloat16* l) {
  __builtin_amdgcn_global_load_lds(
      (const __attribute__((address_space(1))) void*)g,
      (__attribute__((address_space(3))) void*)l, 16, 0, 0);
}

// ---------------------------------------------------------------------------
// cvt: fp32 -> bf16, each element exactly once.  9 jobs.
// ---------------------------------------------------------------------------
struct CvtJob { const float* src; __hip_bfloat16* dst; int n4; };
struct CvtArgs { CvtJob j[9]; };

__global__ __launch_bounds__(256) void cvt_kernel(CvtArgs a) {
  const CvtJob jb = a.j[blockIdx.y];
  const float4* s = (const float4*)jb.src;
  bf16x4* d = (bf16x4*)jb.dst;
  const int stride = gridDim.x * 256;
  for (int i = blockIdx.x * 256 + threadIdx.x; i < jb.n4; i += stride)
    d[i] = cvt4(s[i]);
}

// ---------------------------------------------------------------------------
// proj (128x128 tile, BK=64, single-buffered 32 KiB LDS -> 5 blocks/CU):
// C = (A@W^T + b)*osc.  Residency push (R11 lesson): grid 832 working
// blocks of 256 threads; up to 5 co-resident blocks/CU hide the per-tile
// barrier drains.  4 waves as 2M x 2N, per-wave 64x64, acc[4][4];
// 32 MFMA + 16 ds_read_b128 per tile per wave.  XOR swizzle via
// pre-swizzled gload source (0 conflicts).
// ---------------------------------------------------------------------------
struct Gemm { const __hip_bfloat16* A; const __hip_bfloat16* W;
              const float* bias; __hip_bfloat16* out; int mode; int mBits; int nBlk;
              float oscale; };
struct ProjArgs { Gemm g[5]; };

// stage one 128x64 bf16 tile (row-major, ld=1024) into linear LDS.
// 256 threads x 4 issues x 16B = 16 KiB.  rows = c*32 + wave*8 + (lane>>3).
static __device__ __forceinline__ void stage_tile(const __hip_bfloat16* gtile,
                                                  __hip_bfloat16* ltile,
                                                  int wave, int lane) {
  const int r = lane >> 3;                 // 0..7
  const int chunk = (lane & 7) ^ r;        // pre-swizzled source chunk
#pragma unroll
  for (int c = 0; c < 4; c++) {
    const int rowbase = c * 32 + wave * 8;
    gl_lds16(gtile + (size_t)(rowbase + r) * 1024 + chunk * 8,
             ltile + (size_t)rowbase * 64);   // wave-uniform base + lane*16
  }
}

__global__ __launch_bounds__(256) void proj_kernel(ProjArgs pa) {
  const Gemm g = pa.g[blockIdx.y];
  if ((int)blockIdx.x >= g.nBlk) return;
  __shared__ __hip_bfloat16 As[128][64];   // 16 KiB
  __shared__ __hip_bfloat16 Ws[128][64];   // 16 KiB

  const int bid = blockIdx.x;
  const int m0 = (bid & ((1 << g.mBits) - 1)) * 128;
  const int n0 = (bid >> g.mBits) * 128;
  const int tid = threadIdx.x;
  const int wave = tid >> 6, lane = tid & 63;
  const int q16 = lane >> 4, l16 = lane & 15;
  const int wr = wave >> 1, wc = wave & 1;     // 2 (M) x 2 (N) wave grid
  const int l7 = l16 & 7;

  const __hip_bfloat16* Ag = g.A + (size_t)m0 * 1024;
  const __hip_bfloat16* Wg = g.W + (size_t)n0 * 1024;

  f32x4 acc[4][4] = {};

  for (int t = 0; t < 16; ++t) {
    __syncthreads();   // previous tile's LDS reads complete
    stage_tile(Ag + t * 64, &As[0][0], wave, lane);
    stage_tile(Wg + t * 64, &Ws[0][0], wave, lane);
    __syncthreads();   // staging drained (vmcnt0+lgkm0) and visible
#pragma unroll
    for (int kh = 0; kh < 2; kh++) {
      const int csw = ((kh * 4 + q16) ^ l7) * 8;   // swizzled read column
      bf16x8 bw[4], af[4];
#pragma unroll
      for (int ni = 0; ni < 4; ni++)
        bw[ni] = *(const bf16x8*)(&Ws[wc * 64 + ni * 16 + l16][0] + csw);
#pragma unroll
      for (int mi = 0; mi < 4; mi++)
        af[mi] = *(const bf16x8*)(&As[wr * 64 + mi * 16 + l16][0] + csw);
      __builtin_amdgcn_s_setprio(1);
#pragma unroll
      for (int ni = 0; ni < 4; ni++)
#pragma unroll
        for (int mi = 0; mi < 4; mi++)
          acc[mi][ni] = MFMA_BF16(af[mi], bw[ni], acc[mi][ni], 0, 0, 0);
      __builtin_amdgcn_s_setprio(0);
    }
  }

#pragma unroll
  for (int ni = 0; ni < 4; ni++) {
    const int n = n0 + wc * 64 + ni * 16 + l16;
#pragma unroll
    for (int mi = 0; mi < 4; mi++) {
#pragma unroll
      for (int rr = 0; rr < 4; rr++) {
        const int m = m0 + wr * 64 + mi * 16 + q16 * 4 + rr;
        float val = acc[mi][ni][rr];
        size_t oidx;
        if (g.mode == 0) {
          val = (val + g.bias[n]) * g.oscale;
          const int b = m >> 9, s = m & 511;
          const int h = n >> 6, d = n & 63;
          oidx = ((size_t)((b * 16 + h) * 512 + s)) * 64 + d;
        } else if (g.mode == 1) {
          // operand-swapped V GEMM: m = hid (h,d), n = (b,s)
          val = (val + g.bias[m]) * g.oscale;
          const int b = n >> 9, s = n & 511;
          const int h = m >> 6, d = m & 63;
          oidx = ((size_t)((b * 16 + h) * 64 + d)) * 512 + s;
        } else {
          val = (val + g.bias[n]) * g.oscale;
          const int h = n >> 6, d = n & 63;
          oidx = ((size_t)(h * 512 + m)) * 64 + d;
        }
        g.out[oidx] = f2bf(val);
      }
    }
  }
}

// ---------------------------------------------------------------------------
// attn: flash-style, 2 barriers/iter, pre-sheared cp/p2c stores (round 12).
// ---------------------------------------------------------------------------
__global__ __launch_bounds__(256) void attn_kernel(
    const __hip_bfloat16* __restrict__ ql,   // [B*NH,512,64] (pre-scaled)
    const __hip_bfloat16* __restrict__ kl,   // [B*NH,512,64]
    const __hip_bfloat16* __restrict__ vlT,  // [B*NH,64,512]
    const __hip_bfloat16* __restrict__ pk,   // [NH,512,64]  (rows = jj = q-k)
    const __hip_bfloat16* __restrict__ pq,   // [NH,512,64]  (pre-scaled)
    float* __restrict__ out)                 // [B,S,HID] fp32
{
  __shared__ __align__(16) __hip_bfloat16 pool[2][64][72];   // 18,432
  __shared__ __align__(16) __hip_bfloat16 pqs[2][32][72];    //  9,216
  __shared__ __align__(16) float qkbuf[32][36];              //  4,608
  __shared__ __align__(16) __hip_bfloat16 cpexp[2][32][36];  //  4,608
  __shared__ __align__(16) __hip_bfloat16 pTexp[32][36];     //  2,304
  __shared__ __align__(16) __hip_bfloat16 ptile[32][40];     //  2,560
  __shared__ __align__(16) __hip_bfloat16 vt[64][40];        //  5,120
  __shared__ float mred[32];                                 //    128
  __shared__ float rsum[32];                                 //    128
  // total 47,104 B -> 3 blocks/CU

  const int bid = blockIdx.x;
  const int qt = 15 - (bid >> 7);
  const int bh = bid & 127;
  const int h = bh & 15, b = bh >> 4;
  const int q0 = qt * 32;

  const __hip_bfloat16* qlp = ql + (size_t)bh * 512 * 64;
  const __hip_bfloat16* klp = kl + (size_t)bh * 512 * 64;
  const __hip_bfloat16* vtp = vlT + (size_t)bh * 64 * 512;
  const __hip_bfloat16* pkp = pk + (size_t)h * 512 * 64;
  const __hip_bfloat16* pqp = pq + (size_t)h * 512 * 64;

  const int tid = threadIdx.x, wave = tid >> 6, lane = tid & 63;
  const int q16 = lane >> 4, l16 = lane & 15;
  const int wr = wave & 1, wc = wave >> 1;   // PV wave grid

  // ql B-fragments (cols of the swapped score MFMAs), loop-invariant
  bf16x8 qlB[2][2];
#pragma unroll
  for (int ksi = 0; ksi < 2; ksi++)
#pragma unroll
    for (int bq = 0; bq < 2; bq++)
      qlB[ksi][bq] = ldg8(qlp + (size_t)(q0 + bq * 16 + l16) * 64 + ksi * 32 + q16 * 8);

  const int kEnd = q0 + 32;
  const int nIter = kEnd >> 5;

  const int sr = tid >> 3, sseg = tid & 7;
  const int vr = tid >> 2, vs = tid & 3;
  int4 rKv, rPKv, rPQv, rVt;
  {
    rKv  = ((const int4*)(klp + (size_t)(q0 + sr) * 64))[sseg];
    rPKv = ((const int4*)(pkp + (size_t)(0 + sr) * 64))[sseg];
    rPQv = ((const int4*)(pqp + (size_t)(0 + sr) * 64))[sseg];
    rVt  = ((const int4*)(vtp + (size_t)vr * 512 + q0))[vs];
  }

  // prologue: zero pqs[1] (window "-1"), stage tile 0, prefetch tile 1 regs
  {
    int4 z = {0, 0, 0, 0};
    *(int4*)(&pqs[1][sr][sseg * 8]) = z;
    *(int4*)(&pool[0][sr][sseg * 8])      = rKv;
    *(int4*)(&pool[0][32 + sr][sseg * 8]) = rPKv;
    *(int4*)(&pqs[0][sr][sseg * 8])       = rPQv;
    if (1 < nIter) {
      rKv  = ((const int4*)(klp + (size_t)(q0 - 32 + sr) * 64))[sseg];
      rPKv = ((const int4*)(pkp + (size_t)(32 + sr) * 64))[sseg];
      rPQv = ((const int4*)(pqp + (size_t)(32 + sr) * 64))[sseg];
    }
  }
  __syncthreads();

  const int aq = tid >> 3;           // assembly q-row (fixed per thread)
  const int kb = (tid & 7) * 4;      // assembly k-quad base
  float m_old = -INFINITY, s_part = 0.f;
  f32x4 octx[2] = {};

  for (int it = 0; it < nIter; ++it) {
    const int k0 = q0 - it * 32;
    const int par = it & 1;

    // ===== regionA: PV(it-1) + score MFMAs(it) + C-writes =====
    if (it > 0) {
      float fr[4];
#pragma unroll
      for (int rr = 0; rr < 4; rr++) fr[rr] = mred[wr * 16 + q16 * 4 + rr];
      bf16x8 af = *(const bf16x8*)(&ptile[wr * 16 + l16][q16 * 8]);
#pragma unroll
      for (int cs = 0; cs < 2; cs++) {
        bf16x8 bv = *(const bf16x8*)(&vt[wc * 32 + cs * 16 + l16][q16 * 8]);
        f32x4 c = octx[cs];
#pragma unroll
        for (int rr = 0; rr < 4; rr++) c[rr] *= fr[rr];
        octx[cs] = MFMA_BF16(af, bv, c, 0, 0, 0);
      }
    }
    {
      const int arb = (wave == 1) ? 32 : 0;
      f32x4 a4[2][2] = {};
      __builtin_amdgcn_s_setprio(1);
#pragma unroll
      for (int ksi = 0; ksi < 2; ksi++) {
        const int ko = ksi * 32 + q16 * 8;
        bf16x8 Af0 = *(const bf16x8*)(&pool[par][arb + l16][ko]);
        bf16x8 Af1 = *(const bf16x8*)(&pool[par][arb + 16 + l16][ko]);
        bf16x8 Bf0, Bf1;
        if (wave < 2) {
          Bf0 = qlB[ksi][0];
          Bf1 = qlB[ksi][1];
        } else {
          const int ps = (wave == 2) ? (par ^ 1) : par;
          Bf0 = *(const bf16x8*)(&pqs[ps][l16][ko]);
          Bf1 = *(const bf16x8*)(&pqs[ps][16 + l16][ko]);
        }
        a4[0][0] = MFMA_BF16(Af0, Bf0, a4[0][0], 0, 0, 0);
        a4[0][1] = MFMA_BF16(Af0, Bf1, a4[0][1], 0, 0, 0);
        a4[1][0] = MFMA_BF16(Af1, Bf0, a4[1][0], 0, 0, 0);
        a4[1][1] = MFMA_BF16(Af1, Bf1, a4[1][1], 0, 0, 0);
      }
      __builtin_amdgcn_s_setprio(0);
      if (wave == 0) {
#pragma unroll
        for (int a = 0; a < 2; a++)
#pragma unroll
          for (int bq = 0; bq < 2; bq++)
            *(f32x4*)(&qkbuf[bq * 16 + l16][a * 16 + q16 * 4]) = a4[a][bq];
      } else if (wave == 1) {
        // cp value (q, jr) -> single write: tile it at kl=q-jr (jr<=q),
        // else tile it+1 at kl=q+32-jr
#pragma unroll
        for (int a = 0; a < 2; a++)
#pragma unroll
          for (int bq = 0; bq < 2; bq++) {
            const int q = bq * 16 + l16;
#pragma unroll
            for (int r = 0; r < 4; r++) {
              const int jr = a * 16 + q16 * 4 + r;
              const short val = f2bs(a4[a][bq][r]);
              if (jr <= q) ((short*)&cpexp[par][q][0])[q - jr] = val;
              else         ((short*)&cpexp[par ^ 1][q][0])[q + 32 - jr] = val;
            }
          }
      } else {
        // p2c value (jj_abs, k) -> pTexp[q=k+jj_abs-32][k] when q in [0,32)
        const int jjb = (wave == 3) ? 32 : 0;
#pragma unroll
        for (int a = 0; a < 2; a++)
#pragma unroll
          for (int bq = 0; bq < 2; bq++) {
            const int jj = jjb + bq * 16 + l16;
#pragma unroll
            for (int r = 0; r < 4; r++) {
              const int k = a * 16 + q16 * 4 + r;
              const int q = k + jj - 32;
              if (q >= 0 && q < 32)
                ((short*)&pTexp[q][0])[k] = f2bs(a4[a][bq][r]);
            }
          }
      }
    }
    __syncthreads();   // barB

    // ===== regionB: assembly + online softmax + vt/K/pk/pq staging =====
    {
      const f32x4 qk4 = *(const f32x4*)(&qkbuf[aq][kb]);
      const bf16x4 cp4 = *(const bf16x4*)(&cpexp[par][aq][kb]);
      const bf16x4 p4  = *(const bf16x4*)(&pTexp[aq][kb]);
      float v[4];
      float tmax = -INFINITY;
#pragma unroll
      for (int j = 0; j < 4; j++) {
        v[j] = qk4[j] + s2f(cp4[j]) + s2f(p4[j]);
        const bool msk = (it == 0) && (aq < kb + j);
        if (msk) v[j] = -INFINITY;   // causal mask (garbage cp read discarded)
        else tmax = fmaxf(tmax, v[j]);
      }
      tmax = fmaxf(tmax, __shfl_xor(tmax, 1));
      tmax = fmaxf(tmax, __shfl_xor(tmax, 2));
      tmax = fmaxf(tmax, __shfl_xor(tmax, 4));
      const float m_new = fmaxf(m_old, tmax);
      const float f = __expf(m_old - m_new);   // 0 at it=0 (m_old=-inf)
      bf16x4 pv4;
      float psum = 0.f;
#pragma unroll
      for (int j = 0; j < 4; j++) {
        const float p = __expf(v[j] - m_new);  // masked -> exp(-inf)=0
        pv4[j] = f2bs(p);
        psum += p;
      }
      s_part = s_part * f + psum;
      m_old = m_new;
      *(bf16x4*)(&ptile[aq][kb]) = pv4;
      if ((tid & 7) == 0) mred[aq] = f;
    }
    {  // vt(it) stage + prefetch
      *(int4*)(&vt[vr][vs * 8]) = rVt;
      if (it + 1 < nIter)
        rVt = ((const int4*)(vtp + (size_t)vr * 512 + (k0 - 32)))[vs];
    }
    if (it + 1 < nIter) {   // stage tile it+1 + prefetch tile it+2
      *(int4*)(&pool[par ^ 1][sr][sseg * 8])      = rKv;
      *(int4*)(&pool[par ^ 1][32 + sr][sseg * 8]) = rPKv;
      *(int4*)(&pqs[par ^ 1][sr][sseg * 8])       = rPQv;
      if (it + 2 < nIter) {
        const int k02 = q0 - (it + 2) * 32, jb2 = (it + 2) * 32;
        rKv  = ((const int4*)(klp + (size_t)(k02 + sr) * 64))[sseg];
        rPKv = ((const int4*)(pkp + (size_t)(jb2 + sr) * 64))[sseg];
        rPQv = ((const int4*)(pqp + (size_t)(jb2 + sr) * 64))[sseg];
      }
    }
    __syncthreads();   // barC
  }

  // epilogue PV(nIter-1)
  {
    float fr[4];
#pragma unroll
    for (int rr = 0; rr < 4; rr++) fr[rr] = mred[wr * 16 + q16 * 4 + rr];
    bf16x8 af = *(const bf16x8*)(&ptile[wr * 16 + l16][q16 * 8]);
#pragma unroll
    for (int cs = 0; cs < 2; cs++) {
      bf16x8 bv = *(const bf16x8*)(&vt[wc * 32 + cs * 16 + l16][q16 * 8]);
      f32x4 c = octx[cs];
#pragma unroll
      for (int rr = 0; rr < 4; rr++) c[rr] *= fr[rr];
      octx[cs] = MFMA_BF16(af, bv, c, 0, 0, 0);
    }
  }

  // rowsum reduce (8 threads per row, consecutive lanes)
  {
    float s = s_part;
    s += __shfl_xor(s, 1);
    s += __shfl_xor(s, 2);
    s += __shfl_xor(s, 4);
    if ((tid & 7) == 0) rsum[aq] = s;
  }
  __syncthreads();

  for (int cs = 0; cs < 2; cs++) {
    const int d = wc * 32 + cs * 16 + l16;
    for (int rr = 0; rr < 4; rr++) {
      const int qh = wr * 16 + q16 * 4 + rr;
      const float val = octx[cs][rr] / rsum[qh];
      out[((size_t)(b * 512 + q0 + qh)) * 1024 + h * 64 + d] = val;
    }
  }
}

// ---------------------------------------------------------------------------
extern "C" void kernel_launch(void* const* d_in, const int* in_sizes, int n_in,
                              void* d_out, int out_size, void* d_ws, size_t ws_size,
                              hipStream_t stream) {
  const float* q   = (const float*)d_in[0];
  const float* k   = (const float*)d_in[1];
  const float* v   = (const float*)d_in[2];
  // d_in[3] = attention_mask: deterministic causal tril -> not read
  const float* Wq  = (const float*)d_in[4];
  const float* bq  = (const float*)d_in[5];
  const float* Wk  = (const float*)d_in[6];
  const float* bk  = (const float*)d_in[7];
  const float* Wv  = (const float*)d_in[8];
  const float* bv  = (const float*)d_in[9];
  const float* Wpk = (const float*)d_in[10];
  const float* bpk = (const float*)d_in[11];
  const float* Wpq = (const float*)d_in[12];
  const float* bpq = (const float*)d_in[13];
  const float* rel = (const float*)d_in[14];
  float* out = (float*)d_out;

  char* ws = (char*)d_ws;
  const size_t MB = 1u << 20;
  __hip_bfloat16* bqi  = (__hip_bfloat16*)(ws);
  __hip_bfloat16* bki  = (__hip_bfloat16*)(ws + 8 * MB);
  __hip_bfloat16* bvi  = (__hip_bfloat16*)(ws + 16 * MB);
  __hip_bfloat16* bWq  = (__hip_bfloat16*)(ws + 24 * MB);
  __hip_bfloat16* bWk  = (__hip_bfloat16*)(ws + 26 * MB);
  __hip_bfloat16* bWv  = (__hip_bfloat16*)(ws + 28 * MB);
  __hip_bfloat16* bWpk = (__hip_bfloat16*)(ws + 30 * MB);
  __hip_bfloat16* bWpq = (__hip_bfloat16*)(ws + 32 * MB);
  __hip_bfloat16* brel = (__hip_bfloat16*)(ws + 34 * MB);
  __hip_bfloat16* wql  = (__hip_bfloat16*)(ws + 35 * MB);
  __hip_bfloat16* wkl  = (__hip_bfloat16*)(ws + 43 * MB);
  __hip_bfloat16* wvlT = (__hip_bfloat16*)(ws + 51 * MB);
  __hip_bfloat16* wpk  = (__hip_bfloat16*)(ws + 59 * MB);
  __hip_bfloat16* wpq  = (__hip_bfloat16*)(ws + 60 * MB);

  CvtArgs ca;
  ca.j[0] = { q,   bqi,  4194304 / 4 };
  ca.j[1] = { k,   bki,  4194304 / 4 };
  ca.j[2] = { v,   bvi,  4194304 / 4 };
  ca.j[3] = { Wq,  bWq,  1048576 / 4 };
  ca.j[4] = { Wk,  bWk,  1048576 / 4 };
  ca.j[5] = { Wv,  bWv,  1048576 / 4 };
  ca.j[6] = { Wpk, bWpk, 1048576 / 4 };
  ca.j[7] = { Wpq, bWpq, 1048576 / 4 };
  ca.j[8] = { rel + (size_t)512 * 1024, brel, 524288 / 4 };
  cvt_kernel<<<dim3(1024, 9), 256, 0, stream>>>(ca);

  ProjArgs pj;
  // 128x128 tiles: nBlk = (M/128) * (N/128), mBits = log2(M/128)
  pj.g[0] = { bqi,  bWq,  bq,  wql,  0, 5, 256, SCALE };  // Q pre-scaled (M=4096,N=1024)
  pj.g[1] = { bki,  bWk,  bk,  wkl,  0, 5, 256, 1.0f };
  pj.g[2] = { bWv,  bvi,  bv,  wvlT, 1, 3, 256, 1.0f };   // operand-swapped V (M=1024,N=4096)
  pj.g[3] = { brel, bWpk, bpk, wpk,  2, 2, 32,  1.0f };   // M=512,N=1024
  pj.g[4] = { brel, bWpq, bpq, wpq,  2, 2, 32,  SCALE };  // pq pre-scaled
  proj_kernel<<<dim3(256, 5), 256, 0, stream>>>(pj);

  attn_kernel<<<2048, 256, 0, stream>>>(wql, wkl, wvlT, wpk, wpq, out);
}